// Round 6
// baseline (205.985 us; speedup 1.0000x reference)
//
#include <hip/hip_runtime.h>

#define NN 25000
#define NE 200000
#define ET (NN + NE)
#define NBLK_SCAN ((NN + 255) / 256)   // 98

__device__ __forceinline__ unsigned short f2bf(float f) {
    unsigned u = __float_as_uint(f);
    unsigned r = (u + 0x7fffu + ((u >> 16) & 1u)) >> 16;
    return (unsigned short)r;
}

// ---------- CSR build ----------
__global__ void hist_kernel(const int* __restrict__ edst, int* __restrict__ deg) {
    int e = blockIdx.x * 256 + threadIdx.x;
    if (e >= ET) return;
    int d = (e < NE) ? edst[e] : (e - NE);
    atomicAdd(&deg[d], 1);
}

// single-kernel scan: block-local inclusive scan + atomic range reservation.
__global__ void scan_atomic(const int* __restrict__ deg, int* __restrict__ soff,
                            int* __restrict__ cursor, int* __restrict__ gcount) {
    __shared__ int sh[256];
    __shared__ int base;
    int t = threadIdx.x, i = blockIdx.x * 256 + t;
    int v = (i < NN) ? deg[i] : 0;
    sh[t] = v;
    __syncthreads();
    for (int off = 1; off < 256; off <<= 1) {
        int u = (t >= off) ? sh[t - off] : 0;
        __syncthreads();
        sh[t] += u;
        __syncthreads();
    }
    if (t == 255) base = atomicAdd(gcount, sh[255]);
    __syncthreads();
    if (i < NN) {
        int ex = base + sh[t] - v;
        soff[i] = ex;
        cursor[i] = ex;
    }
}

__global__ void scatter_kernel(const int* __restrict__ esrc, const int* __restrict__ edst,
                               int* __restrict__ cursor, int* __restrict__ srcs) {
    int e = blockIdx.x * 256 + threadIdx.x;
    if (e >= ET) return;
    int s, d;
    if (e < NE) { s = esrc[e]; d = edst[e]; }
    else        { s = e - NE; d = s; }
    int p = atomicAdd(&cursor[d], 1);
    srcs[p] = s;
}

// ---------- xw = bn(x) @ W  (bf16, node-row layout [c][h]) + xu = bn(x) @ U ----------
template<int D, bool BN>
__global__ void xw_kernel(const float* __restrict__ x, const float* __restrict__ W,
                          const float* __restrict__ U, const float* __restrict__ ss,
                          unsigned short* __restrict__ xwb, float* __restrict__ xu) {
    const int NB = 16;
    __shared__ float xs[NB][D];
    __shared__ unsigned short lt[NB][256];  // transposed bf16 rows, layout [c][h]
    int base = blockIdx.x * NB;
    int tid = threadIdx.x;
    int nvalid = min(NB, NN - base);
    for (int i = tid; i < NB * D; i += 256) {
        int n = i / D, k = i % D;
        float v = (n < nvalid) ? x[(size_t)(base + n) * D + k] : 0.f;
        if (BN) v = v * ss[k] + ss[64 + k];
        xs[n][k] = v;
    }
    __syncthreads();
    float acc[NB];
#pragma unroll
    for (int i = 0; i < NB; i++) acc[i] = 0.f;
    int j = tid;                 // GEMM column = h*64 + c
    int h = j >> 6, c = j & 63;
    for (int k = 0; k < D; k++) {
        float w = W[k * 256 + j];
#pragma unroll
        for (int i = 0; i < NB; i++) acc[i] += xs[i][k] * w;
    }
#pragma unroll
    for (int i = 0; i < NB; i++) lt[i][(c << 2) | h] = f2bf(acc[i]);
    // xu: threads 0..63 -> (node, head)
    if (tid < NB * 4) {
        int n = tid >> 2, hh = tid & 3;
        if (n < nvalid) {
            float s = 0.f;
            for (int k = 0; k < D; k++) s += xs[n][k] * U[k * 4 + hh];
            xu[(size_t)(base + n) * 4 + hh] = s;
        }
    }
    __syncthreads();
    // coalesced copy: nvalid rows * 512B; 32 uint4 per row; 2 per thread
    const uint4* s4 = (const uint4*)&lt[0][0];
    uint4* d4 = (uint4*)(xwb + (size_t)base * 256);
    int lim = nvalid * 32;
    if (tid < lim) d4[tid] = s4[tid];
    int t2 = tid + 256;
    if (t2 < lim) d4[t2] = s4[t2];
}

// ---------- per-edge softmax+weighted-sum term ----------
__device__ __forceinline__ float edge_term(const float4& xd, const float4& us, const uint2& rv,
                                           float c0, float c1, float c2, float c3) {
    float l0 = xd.x - us.x + c0;
    float l1 = xd.y - us.y + c1;
    float l2 = xd.z - us.z + c2;
    float l3 = xd.w - us.w + c3;
    float mx = fmaxf(fmaxf(l0, l1), fmaxf(l2, l3));
    float e0 = __expf(l0 - mx), e1 = __expf(l1 - mx), e2 = __expf(l2 - mx), e3 = __expf(l3 - mx);
    float inv = 1.f / (e0 + e1 + e2 + e3);
    float w0 = __uint_as_float(rv.x << 16);
    float w1 = __uint_as_float(rv.x & 0xffff0000u);
    float w2 = __uint_as_float(rv.y << 16);
    float w3 = __uint_as_float(rv.y & 0xffff0000u);
    return inv * (e0 * w0 + e1 * w1 + e2 * w2 + e3 * w3);
}

// ---------- edge aggregation: wave per dst, dual-issue gather ----------
template<bool RELU_BN>
__global__ void edge_kernel(const int* __restrict__ soff, const int* __restrict__ deg,
                            const int* __restrict__ srcs,
                            const unsigned short* __restrict__ xwb, const float* __restrict__ xu,
                            const float* __restrict__ cvec, const float* __restrict__ bias,
                            float* __restrict__ y, float* __restrict__ bnpart) {
    int wid = threadIdx.x >> 6, lane = threadIdx.x & 63;
    int d = blockIdx.x * 4 + wid;  // grid 6250 * 4 waves == 25000 exactly
    __shared__ float sbuf[4][64], sqbuf[4][64];

    float c0 = cvec[0], c1 = cvec[1], c2 = cvec[2], c3 = cvec[3];
    int cnt = deg[d];
    int beg = soff[d], end = beg + cnt;
    float4 xd = *(const float4*)&xu[(size_t)d << 2];

    float acc = 0.f;
    int i = beg;
    for (; i + 2 <= end; i += 2) {
        int sa = srcs[i], sb = srcs[i + 1];
        float4 ua = *(const float4*)&xu[(size_t)sa << 2];
        uint2 ra = *(const uint2*)(xwb + ((size_t)sa << 8) + (lane << 2));
        float4 ub = *(const float4*)&xu[(size_t)sb << 2];
        uint2 rb = *(const uint2*)(xwb + ((size_t)sb << 8) + (lane << 2));
        acc += edge_term(xd, ua, ra, c0, c1, c2, c3);
        acc += edge_term(xd, ub, rb, c0, c1, c2, c3);
    }
    if (i < end) {
        int sa = srcs[i];
        float4 ua = *(const float4*)&xu[(size_t)sa << 2];
        uint2 ra = *(const uint2*)(xwb + ((size_t)sa << 8) + (lane << 2));
        acc += edge_term(xd, ua, ra, c0, c1, c2, c3);
    }

    float v = acc / (float)cnt + bias[lane];
    if (RELU_BN) v = fmaxf(v, 0.f);
    y[(size_t)d * 64 + lane] = v;

    if (RELU_BN) {
        sbuf[wid][lane] = v;
        sqbuf[wid][lane] = v * v;
        __syncthreads();
        if (threadIdx.x < 64) {
            float ts = sbuf[0][threadIdx.x] + sbuf[1][threadIdx.x] + sbuf[2][threadIdx.x] + sbuf[3][threadIdx.x];
            float tq = sqbuf[0][threadIdx.x] + sqbuf[1][threadIdx.x] + sqbuf[2][threadIdx.x] + sqbuf[3][threadIdx.x];
            int p = blockIdx.x & 63;
            atomicAdd(&bnpart[p * 128 + threadIdx.x], ts);
            atomicAdd(&bnpart[p * 128 + 64 + threadIdx.x], tq);
        }
    }
}

// ---------- BN stats -> scale/shift; re-zeroes bnpart for the next layer ----------
__global__ void bnprep(float* __restrict__ bnpart, const float* __restrict__ g,
                       const float* __restrict__ be, float* __restrict__ ss) {
    __shared__ float sb[4][64], qb[4][64];
    int t = threadIdx.x, grp = t >> 6, ch = t & 63;
    float s = 0.f, q = 0.f;
    for (int p = grp * 16; p < grp * 16 + 16; p++) {
        s += bnpart[p * 128 + ch];
        q += bnpart[p * 128 + 64 + ch];
        bnpart[p * 128 + ch] = 0.f;
        bnpart[p * 128 + 64 + ch] = 0.f;
    }
    sb[grp][ch] = s;
    qb[grp][ch] = q;
    __syncthreads();
    if (t < 64) {
        float S = sb[0][t] + sb[1][t] + sb[2][t] + sb[3][t];
        float Q = qb[0][t] + qb[1][t] + qb[2][t] + qb[3][t];
        float m = S * (1.0f / NN);
        float var = Q * (1.0f / NN) - m * m;
        float sc = g[t] * rsqrtf(var + 1e-5f);
        ss[t] = sc;
        ss[64 + t] = be[t] - m * sc;
    }
}

extern "C" void kernel_launch(void* const* d_in, const int* in_sizes, int n_in,
                              void* d_out, int out_size, void* d_ws, size_t ws_size,
                              hipStream_t stream) {
    const float* x    = (const float*)d_in[0];
    const int*   ei   = (const int*)d_in[1];
    const int*   esrc = ei;
    const int*   edst = ei + NE;
    const float* w0 = (const float*)d_in[2];
    const float* u0 = (const float*)d_in[3];
    const float* c0 = (const float*)d_in[4];
    const float* b0 = (const float*)d_in[5];
    const float* w1 = (const float*)d_in[6];
    const float* u1 = (const float*)d_in[7];
    const float* c1 = (const float*)d_in[8];
    const float* b1 = (const float*)d_in[9];
    const float* w2 = (const float*)d_in[10];
    const float* u2 = (const float*)d_in[11];
    const float* c2 = (const float*)d_in[12];
    const float* b2 = (const float*)d_in[13];
    const float* g0 = (const float*)d_in[14];
    const float* be0= (const float*)d_in[15];
    const float* g1 = (const float*)d_in[16];
    const float* be1= (const float*)d_in[17];
    float* out = (float*)d_out;

    char* ws = (char*)d_ws;
    size_t off = 0;
    auto alloc = [&](size_t bytes) { char* p = ws + off; off += (bytes + 255) & ~(size_t)255; return p; };
    float*          xu     = (float*)alloc((size_t)NN * 4 * sizeof(float));
    float*          y      = (float*)alloc((size_t)NN * 64 * sizeof(float));
    unsigned short* xwb    = (unsigned short*)alloc((size_t)NN * 256 * sizeof(unsigned short));
    int*            ints   = (int*)alloc((size_t)(NN + 1) * sizeof(int));  // deg | gcount
    int*            deg    = ints;
    int*            gcount = ints + NN;
    int*            soff   = (int*)alloc((size_t)NN * sizeof(int));
    int*            cursor = (int*)alloc((size_t)NN * sizeof(int));
    int*            srcs   = (int*)alloc((size_t)ET * sizeof(int));
    float*          bnpart = (float*)alloc(64 * 128 * sizeof(float));
    float*          ss     = (float*)alloc(128 * sizeof(float));

    const int EG = (ET + 255) / 256;

    // ---- CSR build (dst-sorted; shared by all 3 layers) ----
    hipMemsetAsync(ints, 0, (size_t)(NN + 1) * sizeof(int), stream);
    hipMemsetAsync(bnpart, 0, 64 * 128 * sizeof(float), stream);
    hist_kernel<<<EG, 256, 0, stream>>>(edst, deg);
    scan_atomic<<<NBLK_SCAN, 256, 0, stream>>>(deg, soff, cursor, gcount);
    scatter_kernel<<<EG, 256, 0, stream>>>(esrc, edst, cursor, srcs);

    const int XG = (NN + 15) / 16;

    // ---- layer 0 (D=32, no BN on input) ----
    xw_kernel<32, false><<<XG, 256, 0, stream>>>(x, w0, u0, nullptr, xwb, xu);
    edge_kernel<true><<<NN / 4, 256, 0, stream>>>(soff, deg, srcs, xwb, xu, c0, b0, y, bnpart);
    bnprep<<<1, 256, 0, stream>>>(bnpart, g0, be0, ss);

    // ---- layer 1 (D=64, BN0 applied on load) ----
    xw_kernel<64, true><<<XG, 256, 0, stream>>>(y, w1, u1, ss, xwb, xu);
    edge_kernel<true><<<NN / 4, 256, 0, stream>>>(soff, deg, srcs, xwb, xu, c1, b1, y, bnpart);
    bnprep<<<1, 256, 0, stream>>>(bnpart, g1, be1, ss);

    // ---- layer 2 (D=64, BN1 applied on load, raw output) ----
    xw_kernel<64, true><<<XG, 256, 0, stream>>>(y, w2, u2, ss, xwb, xu);
    edge_kernel<false><<<NN / 4, 256, 0, stream>>>(soff, deg, srcs, xwb, xu, c2, b2, out, nullptr);
}

// Round 7
// 192.177 us; speedup vs baseline: 1.0718x; 1.0718x over previous
//
#include <hip/hip_runtime.h>

#define NN 25000
#define NE 200000
#define ET (NN + NE)
#define NBLK_SCAN ((NN + 255) / 256)   // 98

typedef float floatx2 __attribute__((ext_vector_type(2)));

__device__ __forceinline__ unsigned short f2bf(float f) {
    unsigned u = __float_as_uint(f);
    unsigned r = (u + 0x7fffu + ((u >> 16) & 1u)) >> 16;
    return (unsigned short)r;
}
__device__ __forceinline__ unsigned char f2fp8(float f) {
    int p = __builtin_amdgcn_cvt_pk_fp8_f32(f, f, 0, false);
    return (unsigned char)(p & 0xff);
}

// ---------- CSR build ----------
__global__ void hist_kernel(const int* __restrict__ edst, int* __restrict__ deg) {
    int e = blockIdx.x * 256 + threadIdx.x;
    if (e >= ET) return;
    int d = (e < NE) ? edst[e] : (e - NE);
    atomicAdd(&deg[d], 1);
}

__global__ void scan_atomic(const int* __restrict__ deg, int* __restrict__ soff,
                            int* __restrict__ cursor, int* __restrict__ gcount) {
    __shared__ int sh[256];
    __shared__ int base;
    int t = threadIdx.x, i = blockIdx.x * 256 + t;
    int v = (i < NN) ? deg[i] : 0;
    sh[t] = v;
    __syncthreads();
    for (int off = 1; off < 256; off <<= 1) {
        int u = (t >= off) ? sh[t - off] : 0;
        __syncthreads();
        sh[t] += u;
        __syncthreads();
    }
    if (t == 255) base = atomicAdd(gcount, sh[255]);
    __syncthreads();
    if (i < NN) {
        int ex = base + sh[t] - v;
        soff[i] = ex;
        cursor[i] = ex;
    }
}

__global__ void scatter_kernel(const int* __restrict__ esrc, const int* __restrict__ edst,
                               int* __restrict__ cursor, int* __restrict__ srcs) {
    int e = blockIdx.x * 256 + threadIdx.x;
    if (e >= ET) return;
    int s, d;
    if (e < NE) { s = esrc[e]; d = edst[e]; }
    else        { s = e - NE; d = s; }
    int p = atomicAdd(&cursor[d], 1);
    srcs[p] = s;
}

// ---------- xw = bn(x) @ W  (node-row layout [c][h], fp8 or bf16) + xu = bn(x) @ U ----------
template<int D, bool BN, bool FP8>
__global__ void xw_kernel(const float* __restrict__ x, const float* __restrict__ W,
                          const float* __restrict__ U, const float* __restrict__ ss,
                          void* __restrict__ xwb, float* __restrict__ xu) {
    const int NB = 16;
    __shared__ float xs[NB][D];
    __shared__ unsigned char lt[NB * 512];  // transposed rows: bf16 512B/row, fp8 256B/row
    int base = blockIdx.x * NB;
    int tid = threadIdx.x;
    int nvalid = min(NB, NN - base);
    for (int i = tid; i < NB * D; i += 256) {
        int n = i / D, k = i % D;
        float v = (n < nvalid) ? x[(size_t)(base + n) * D + k] : 0.f;
        if (BN) v = v * ss[k] + ss[64 + k];
        xs[n][k] = v;
    }
    __syncthreads();
    float acc[NB];
#pragma unroll
    for (int i = 0; i < NB; i++) acc[i] = 0.f;
    int j = tid;                 // GEMM column = h*64 + c
    int h = j >> 6, c = j & 63;
    for (int k = 0; k < D; k++) {
        float w = W[k * 256 + j];
#pragma unroll
        for (int i = 0; i < NB; i++) acc[i] += xs[i][k] * w;
    }
    if (FP8) {
        unsigned char* ltb = lt;
#pragma unroll
        for (int i = 0; i < NB; i++) ltb[i * 256 + ((c << 2) | h)] = f2fp8(acc[i]);
    } else {
        unsigned short* ltb = (unsigned short*)lt;
#pragma unroll
        for (int i = 0; i < NB; i++) ltb[i * 256 + ((c << 2) | h)] = f2bf(acc[i]);
    }
    // xu: threads 0..63 -> (node, head)
    if (tid < NB * 4) {
        int n = tid >> 2, hh = tid & 3;
        if (n < nvalid) {
            float s = 0.f;
            for (int k = 0; k < D; k++) s += xs[n][k] * U[k * 4 + hh];
            xu[(size_t)(base + n) * 4 + hh] = s;
        }
    }
    __syncthreads();
    // coalesced copy out
    const int ROWB = FP8 ? 256 : 512;            // bytes per node row
    const uint4* s4 = (const uint4*)lt;
    uint4* d4 = (uint4*)((char*)xwb + (size_t)base * ROWB);
    int lim = nvalid * (ROWB / 16);
    for (int t = tid; t < lim; t += 256) d4[t] = s4[t];
}

// ---------- per-edge softmax+weighted-sum terms ----------
__device__ __forceinline__ float att4(const float4& xd, const float4& us,
                                      float c0, float c1, float c2, float c3,
                                      float& e0, float& e1, float& e2, float& e3) {
    float l0 = xd.x - us.x + c0;
    float l1 = xd.y - us.y + c1;
    float l2 = xd.z - us.z + c2;
    float l3 = xd.w - us.w + c3;
    float mx = fmaxf(fmaxf(l0, l1), fmaxf(l2, l3));
    e0 = __expf(l0 - mx); e1 = __expf(l1 - mx); e2 = __expf(l2 - mx); e3 = __expf(l3 - mx);
    return 1.f / (e0 + e1 + e2 + e3);
}
__device__ __forceinline__ float term_bf16(const float4& xd, const float4& us, uint2 rv,
                                           float c0, float c1, float c2, float c3) {
    float e0, e1, e2, e3;
    float inv = att4(xd, us, c0, c1, c2, c3, e0, e1, e2, e3);
    float w0 = __uint_as_float(rv.x << 16);
    float w1 = __uint_as_float(rv.x & 0xffff0000u);
    float w2 = __uint_as_float(rv.y << 16);
    float w3 = __uint_as_float(rv.y & 0xffff0000u);
    return inv * (e0 * w0 + e1 * w1 + e2 * w2 + e3 * w3);
}
__device__ __forceinline__ float term_fp8(const float4& xd, const float4& us, unsigned rv,
                                          float c0, float c1, float c2, float c3) {
    float e0, e1, e2, e3;
    float inv = att4(xd, us, c0, c1, c2, c3, e0, e1, e2, e3);
    floatx2 lo = __builtin_amdgcn_cvt_pk_f32_fp8((int)rv, false);  // heads 0,1
    floatx2 hi = __builtin_amdgcn_cvt_pk_f32_fp8((int)rv, true);   // heads 2,3
    return inv * (e0 * lo.x + e1 * lo.y + e2 * hi.x + e3 * hi.y);
}

// ---------- edge aggregation: wave per dst, dual-issue gather ----------
template<bool RELU_BN, bool FP8>
__global__ void edge_kernel(const int* __restrict__ soff, const int* __restrict__ deg,
                            const int* __restrict__ srcs,
                            const void* __restrict__ xwb, const float* __restrict__ xu,
                            const float* __restrict__ cvec, const float* __restrict__ bias,
                            float* __restrict__ y, float* __restrict__ bnpart) {
    int wid = threadIdx.x >> 6, lane = threadIdx.x & 63;
    int d = blockIdx.x * 4 + wid;  // grid 6250 * 4 waves == 25000 exactly
    __shared__ float sbuf[4][64], sqbuf[4][64];

    float c0 = cvec[0], c1 = cvec[1], c2 = cvec[2], c3 = cvec[3];
    int cnt = deg[d];
    int beg = soff[d], end = beg + cnt;
    float4 xd = *(const float4*)&xu[(size_t)d << 2];
    const char* xb = (const char*)xwb;

    float acc = 0.f;
    int i = beg;
    if (FP8) {
        for (; i + 2 <= end; i += 2) {
            int sa = srcs[i], sb = srcs[i + 1];
            float4 ua = *(const float4*)&xu[(size_t)sa << 2];
            unsigned ra = *(const unsigned*)(xb + ((size_t)sa << 8) + (lane << 2));
            float4 ub = *(const float4*)&xu[(size_t)sb << 2];
            unsigned rb = *(const unsigned*)(xb + ((size_t)sb << 8) + (lane << 2));
            acc += term_fp8(xd, ua, ra, c0, c1, c2, c3);
            acc += term_fp8(xd, ub, rb, c0, c1, c2, c3);
        }
        if (i < end) {
            int sa = srcs[i];
            float4 ua = *(const float4*)&xu[(size_t)sa << 2];
            unsigned ra = *(const unsigned*)(xb + ((size_t)sa << 8) + (lane << 2));
            acc += term_fp8(xd, ua, ra, c0, c1, c2, c3);
        }
    } else {
        for (; i + 2 <= end; i += 2) {
            int sa = srcs[i], sb = srcs[i + 1];
            float4 ua = *(const float4*)&xu[(size_t)sa << 2];
            uint2 ra = *(const uint2*)(xb + ((size_t)sa << 9) + (lane << 3));
            float4 ub = *(const float4*)&xu[(size_t)sb << 2];
            uint2 rb = *(const uint2*)(xb + ((size_t)sb << 9) + (lane << 3));
            acc += term_bf16(xd, ua, ra, c0, c1, c2, c3);
            acc += term_bf16(xd, ub, rb, c0, c1, c2, c3);
        }
        if (i < end) {
            int sa = srcs[i];
            float4 ua = *(const float4*)&xu[(size_t)sa << 2];
            uint2 ra = *(const uint2*)(xb + ((size_t)sa << 9) + (lane << 3));
            acc += term_bf16(xd, ua, ra, c0, c1, c2, c3);
        }
    }

    float v = acc / (float)cnt + bias[lane];
    if (RELU_BN) v = fmaxf(v, 0.f);
    y[(size_t)d * 64 + lane] = v;

    if (RELU_BN) {
        sbuf[wid][lane] = v;
        sqbuf[wid][lane] = v * v;
        __syncthreads();
        if (threadIdx.x < 64) {
            float ts = sbuf[0][threadIdx.x] + sbuf[1][threadIdx.x] + sbuf[2][threadIdx.x] + sbuf[3][threadIdx.x];
            float tq = sqbuf[0][threadIdx.x] + sqbuf[1][threadIdx.x] + sqbuf[2][threadIdx.x] + sqbuf[3][threadIdx.x];
            int p = blockIdx.x & 63;
            atomicAdd(&bnpart[p * 128 + threadIdx.x], ts);
            atomicAdd(&bnpart[p * 128 + 64 + threadIdx.x], tq);
        }
    }
}

// ---------- BN stats -> scale/shift; re-zeroes bnpart for the next layer ----------
__global__ void bnprep(float* __restrict__ bnpart, const float* __restrict__ g,
                       const float* __restrict__ be, float* __restrict__ ss) {
    __shared__ float sb[4][64], qb[4][64];
    int t = threadIdx.x, grp = t >> 6, ch = t & 63;
    float s = 0.f, q = 0.f;
    for (int p = grp * 16; p < grp * 16 + 16; p++) {
        s += bnpart[p * 128 + ch];
        q += bnpart[p * 128 + 64 + ch];
        bnpart[p * 128 + ch] = 0.f;
        bnpart[p * 128 + 64 + ch] = 0.f;
    }
    sb[grp][ch] = s;
    qb[grp][ch] = q;
    __syncthreads();
    if (t < 64) {
        float S = sb[0][t] + sb[1][t] + sb[2][t] + sb[3][t];
        float Q = qb[0][t] + qb[1][t] + qb[2][t] + qb[3][t];
        float m = S * (1.0f / NN);
        float var = Q * (1.0f / NN) - m * m;
        float sc = g[t] * rsqrtf(var + 1e-5f);
        ss[t] = sc;
        ss[64 + t] = be[t] - m * sc;
    }
}

extern "C" void kernel_launch(void* const* d_in, const int* in_sizes, int n_in,
                              void* d_out, int out_size, void* d_ws, size_t ws_size,
                              hipStream_t stream) {
    const float* x    = (const float*)d_in[0];
    const int*   ei   = (const int*)d_in[1];
    const int*   esrc = ei;
    const int*   edst = ei + NE;
    const float* w0 = (const float*)d_in[2];
    const float* u0 = (const float*)d_in[3];
    const float* c0 = (const float*)d_in[4];
    const float* b0 = (const float*)d_in[5];
    const float* w1 = (const float*)d_in[6];
    const float* u1 = (const float*)d_in[7];
    const float* c1 = (const float*)d_in[8];
    const float* b1 = (const float*)d_in[9];
    const float* w2 = (const float*)d_in[10];
    const float* u2 = (const float*)d_in[11];
    const float* c2 = (const float*)d_in[12];
    const float* b2 = (const float*)d_in[13];
    const float* g0 = (const float*)d_in[14];
    const float* be0= (const float*)d_in[15];
    const float* g1 = (const float*)d_in[16];
    const float* be1= (const float*)d_in[17];
    float* out = (float*)d_out;

    char* ws = (char*)d_ws;
    size_t off = 0;
    auto alloc = [&](size_t bytes) { char* p = ws + off; off += (bytes + 255) & ~(size_t)255; return p; };
    // ints and bnpart adjacent -> single zeroing memset
    int*            ints   = (int*)alloc((size_t)(NN + 1) * sizeof(int));  // deg | gcount
    int*            deg    = ints;
    int*            gcount = ints + NN;
    float*          bnpart = (float*)alloc(64 * 128 * sizeof(float));
    size_t zero_bytes = (size_t)((char*)bnpart - (char*)ints) + 64 * 128 * sizeof(float);
    float*          xu     = (float*)alloc((size_t)NN * 4 * sizeof(float));
    float*          y      = (float*)alloc((size_t)NN * 64 * sizeof(float));
    void*           xwb    = (void*)alloc((size_t)NN * 512);   // bf16 rows (fp8 uses half)
    int*            soff   = (int*)alloc((size_t)NN * sizeof(int));
    int*            cursor = (int*)alloc((size_t)NN * sizeof(int));
    int*            srcs   = (int*)alloc((size_t)ET * sizeof(int));
    float*          ss     = (float*)alloc(128 * sizeof(float));

    const int EG = (ET + 255) / 256;
    const int XG = (NN + 15) / 16;

    // ---- CSR build (dst-sorted; shared by all 3 layers) ----
    hipMemsetAsync(ints, 0, zero_bytes, stream);
    hist_kernel<<<EG, 256, 0, stream>>>(edst, deg);
    scan_atomic<<<NBLK_SCAN, 256, 0, stream>>>(deg, soff, cursor, gcount);
    scatter_kernel<<<EG, 256, 0, stream>>>(esrc, edst, cursor, srcs);

    // ---- layer 0 (D=32, no input BN, fp8 messages) ----
    xw_kernel<32, false, true><<<XG, 256, 0, stream>>>(x, w0, u0, nullptr, xwb, xu);
    edge_kernel<true, true><<<NN / 4, 256, 0, stream>>>(soff, deg, srcs, xwb, xu, c0, b0, y, bnpart);
    bnprep<<<1, 256, 0, stream>>>(bnpart, g0, be0, ss);

    // ---- layer 1 (D=64, BN0 on load, fp8 messages) ----
    xw_kernel<64, true, true><<<XG, 256, 0, stream>>>(y, w1, u1, ss, xwb, xu);
    edge_kernel<true, true><<<NN / 4, 256, 0, stream>>>(soff, deg, srcs, xwb, xu, c1, b1, y, bnpart);
    bnprep<<<1, 256, 0, stream>>>(bnpart, g1, be1, ss);

    // ---- layer 2 (D=64, BN1 on load, bf16 messages, raw output) ----
    xw_kernel<64, true, false><<<XG, 256, 0, stream>>>(y, w2, u2, ss, xwb, xu);
    edge_kernel<false, false><<<NN / 4, 256, 0, stream>>>(soff, deg, srcs, xwb, xu, c2, b2, out, nullptr);
}

// Round 9
// 182.834 us; speedup vs baseline: 1.1266x; 1.0511x over previous
//
#include <hip/hip_runtime.h>

#define NN 25000
#define NE 200000
#define ET (NN + NE)
#define NBLK_SCAN ((NN + 255) / 256)   // 98

typedef float floatx2 __attribute__((ext_vector_type(2)));

__device__ __forceinline__ unsigned short f2bf(float f) {
    unsigned u = __float_as_uint(f);
    unsigned r = (u + 0x7fffu + ((u >> 16) & 1u)) >> 16;
    return (unsigned short)r;
}
__device__ __forceinline__ unsigned char f2fp8(float f) {
    int p = __builtin_amdgcn_cvt_pk_fp8_f32(f, f, 0, false);
    return (unsigned char)(p & 0xff);
}

// ---------- CSR build ----------
__global__ void hist_kernel(const int* __restrict__ edst, int* __restrict__ deg) {
    int e = blockIdx.x * 256 + threadIdx.x;
    if (e >= ET) return;
    int d = (e < NE) ? edst[e] : (e - NE);
    atomicAdd(&deg[d], 1);
}

__global__ void scan_atomic(const int* __restrict__ deg, int* __restrict__ soff,
                            int* __restrict__ cursor, int* __restrict__ gcount) {
    __shared__ int sh[256];
    __shared__ int base;
    int t = threadIdx.x, i = blockIdx.x * 256 + t;
    int v = (i < NN) ? deg[i] : 0;
    sh[t] = v;
    __syncthreads();
    for (int off = 1; off < 256; off <<= 1) {
        int u = (t >= off) ? sh[t - off] : 0;
        __syncthreads();
        sh[t] += u;
        __syncthreads();
    }
    if (t == 255) base = atomicAdd(gcount, sh[255]);
    __syncthreads();
    if (i < NN) {
        int ex = base + sh[t] - v;
        soff[i] = ex;
        cursor[i] = ex;
    }
}

__global__ void scatter_kernel(const int* __restrict__ esrc, const int* __restrict__ edst,
                               int* __restrict__ cursor, int* __restrict__ srcs) {
    int e = blockIdx.x * 256 + threadIdx.x;
    if (e >= ET) return;
    int s, d;
    if (e < NE) { s = esrc[e]; d = edst[e]; }
    else        { s = e - NE; d = s; }
    int p = atomicAdd(&cursor[d], 1);
    srcs[p] = s;
}

// ---------- xw = bn(x) @ W + xu = bn(x) @ U; BN folded from bnpart partials ----------
// FP8: 256B/row fp8 [c][h]; else 512B/row bf16 [c][h].
template<int D, bool BN, bool FP8>
__global__ void xw_kernel(const float* __restrict__ x, const float* __restrict__ W,
                          const float* __restrict__ U, const float* __restrict__ bnpartIn,
                          const float* __restrict__ g, const float* __restrict__ be,
                          unsigned char* __restrict__ xwb, float* __restrict__ xu) {
    const int NB = 16;
    __shared__ float xs[NB][D];
    __shared__ unsigned char lt[NB * (FP8 ? 256 : 512)];
    __shared__ float ssm[128];
    int tid = threadIdx.x;

    if (BN) {  // fold bnprep: reduce 64x128 partials -> scale/shift in LDS
        __shared__ float sb[4][64], qb[4][64];
        int grp = tid >> 6, ch = tid & 63;
        float s = 0.f, q = 0.f;
        for (int p = grp * 16; p < grp * 16 + 16; p++) {
            s += bnpartIn[p * 128 + ch];
            q += bnpartIn[p * 128 + 64 + ch];
        }
        sb[grp][ch] = s;
        qb[grp][ch] = q;
        __syncthreads();
        if (tid < 64) {
            float S = sb[0][tid] + sb[1][tid] + sb[2][tid] + sb[3][tid];
            float Q = qb[0][tid] + qb[1][tid] + qb[2][tid] + qb[3][tid];
            float m = S * (1.0f / NN);
            float var = Q * (1.0f / NN) - m * m;
            float sc = g[tid] * rsqrtf(var + 1e-5f);
            ssm[tid] = sc;
            ssm[64 + tid] = be[tid] - m * sc;
        }
        __syncthreads();
    }

    int base = blockIdx.x * NB;
    int nvalid = min(NB, NN - base);
    for (int i = tid; i < NB * D; i += 256) {
        int n = i / D, k = i % D;
        float v = (n < nvalid) ? x[(size_t)(base + n) * D + k] : 0.f;
        if (BN) v = v * ssm[k] + ssm[64 + k];
        xs[n][k] = v;
    }
    __syncthreads();
    float acc[NB];
#pragma unroll
    for (int i = 0; i < NB; i++) acc[i] = 0.f;
    int j = tid;                 // GEMM column = h*64 + c
    int h = j >> 6, c = j & 63;
    for (int k = 0; k < D; k++) {
        float w = W[k * 256 + j];
#pragma unroll
        for (int i = 0; i < NB; i++) acc[i] += xs[i][k] * w;
    }
    if (FP8) {
#pragma unroll
        for (int i = 0; i < NB; i++) lt[i * 256 + ((c << 2) | h)] = f2fp8(acc[i]);
    } else {
        unsigned short* ltb = (unsigned short*)lt;
#pragma unroll
        for (int i = 0; i < NB; i++) ltb[i * 256 + ((c << 2) | h)] = f2bf(acc[i]);
    }
    // xu: threads 0..63 -> (node, head)
    if (tid < NB * 4) {
        int n = tid >> 2, hh = tid & 3;
        if (n < nvalid) {
            float s = 0.f;
            for (int k = 0; k < D; k++) s += xs[n][k] * U[k * 4 + hh];
            xu[(size_t)(base + n) * 4 + hh] = s;
        }
    }
    __syncthreads();
    const int ROWB = FP8 ? 256 : 512;
    const uint4* s4 = (const uint4*)lt;
    uint4* d4 = (uint4*)(xwb + (size_t)base * ROWB);
    int lim = nvalid * (ROWB / 16);
    for (int t = tid; t < lim; t += 256) d4[t] = s4[t];
}

// ---------- per-edge softmax+weighted-sum terms ----------
__device__ __forceinline__ float att4(const float4& xd, const float4& us,
                                      float c0, float c1, float c2, float c3,
                                      float& e0, float& e1, float& e2, float& e3) {
    float l0 = xd.x - us.x + c0;
    float l1 = xd.y - us.y + c1;
    float l2 = xd.z - us.z + c2;
    float l3 = xd.w - us.w + c3;
    float mx = fmaxf(fmaxf(l0, l1), fmaxf(l2, l3));
    e0 = __expf(l0 - mx); e1 = __expf(l1 - mx); e2 = __expf(l2 - mx); e3 = __expf(l3 - mx);
    return 1.f / (e0 + e1 + e2 + e3);
}
__device__ __forceinline__ float term_fp8(const float4& xd, const float4& us, unsigned rv,
                                          float c0, float c1, float c2, float c3) {
    float e0, e1, e2, e3;
    float inv = att4(xd, us, c0, c1, c2, c3, e0, e1, e2, e3);
    floatx2 lo = __builtin_amdgcn_cvt_pk_f32_fp8((int)rv, false);  // heads 0,1
    floatx2 hi = __builtin_amdgcn_cvt_pk_f32_fp8((int)rv, true);   // heads 2,3
    return inv * (e0 * lo.x + e1 * lo.y + e2 * hi.x + e3 * hi.y);
}
__device__ __forceinline__ float term_bf16(const float4& xd, const float4& us, uint2 rv,
                                           float c0, float c1, float c2, float c3) {
    float e0, e1, e2, e3;
    float inv = att4(xd, us, c0, c1, c2, c3, e0, e1, e2, e3);
    float w0 = __uint_as_float(rv.x << 16);
    float w1 = __uint_as_float(rv.x & 0xffff0000u);
    float w2 = __uint_as_float(rv.y << 16);
    float w3 = __uint_as_float(rv.y & 0xffff0000u);
    return inv * (e0 * w0 + e1 * w1 + e2 * w2 + e3 * w3);
}

// ---------- edge aggregation: wave per dst, 4-wide issue ----------
template<bool RELU_BN, bool FP8>
__global__ void edge_kernel(const int* __restrict__ soff, const int* __restrict__ deg,
                            const int* __restrict__ srcs,
                            const unsigned char* __restrict__ xwb, const float* __restrict__ xu,
                            const float* __restrict__ cvec, const float* __restrict__ bias,
                            float* __restrict__ y, float* __restrict__ bnpart) {
    int wid = threadIdx.x >> 6, lane = threadIdx.x & 63;
    int d = blockIdx.x * 4 + wid;  // grid 6250 * 4 waves == 25000 exactly
    __shared__ float sbuf[4][64], sqbuf[4][64];

    float c0 = cvec[0], c1 = cvec[1], c2 = cvec[2], c3 = cvec[3];
    int cnt = deg[d];
    int beg = soff[d], end = beg + cnt;
    float4 xd = *(const float4*)&xu[(size_t)d << 2];

    float acc = 0.f;
    int i = beg;
    if (FP8) {
        for (; i + 4 <= end; i += 4) {
            int s0 = srcs[i], s1 = srcs[i + 1], s2 = srcs[i + 2], s3 = srcs[i + 3];
            float4 u0 = *(const float4*)&xu[(size_t)s0 << 2];
            unsigned r0 = *(const unsigned*)(xwb + ((size_t)s0 << 8) + (lane << 2));
            float4 u1 = *(const float4*)&xu[(size_t)s1 << 2];
            unsigned r1 = *(const unsigned*)(xwb + ((size_t)s1 << 8) + (lane << 2));
            float4 u2 = *(const float4*)&xu[(size_t)s2 << 2];
            unsigned r2 = *(const unsigned*)(xwb + ((size_t)s2 << 8) + (lane << 2));
            float4 u3 = *(const float4*)&xu[(size_t)s3 << 2];
            unsigned r3 = *(const unsigned*)(xwb + ((size_t)s3 << 8) + (lane << 2));
            acc += term_fp8(xd, u0, r0, c0, c1, c2, c3);
            acc += term_fp8(xd, u1, r1, c0, c1, c2, c3);
            acc += term_fp8(xd, u2, r2, c0, c1, c2, c3);
            acc += term_fp8(xd, u3, r3, c0, c1, c2, c3);
        }
        for (; i < end; i++) {
            int s0 = srcs[i];
            float4 u0 = *(const float4*)&xu[(size_t)s0 << 2];
            unsigned r0 = *(const unsigned*)(xwb + ((size_t)s0 << 8) + (lane << 2));
            acc += term_fp8(xd, u0, r0, c0, c1, c2, c3);
        }
    } else {
        for (; i + 4 <= end; i += 4) {
            int s0 = srcs[i], s1 = srcs[i + 1], s2 = srcs[i + 2], s3 = srcs[i + 3];
            float4 u0 = *(const float4*)&xu[(size_t)s0 << 2];
            uint2 r0 = *(const uint2*)(xwb + ((size_t)s0 << 9) + (lane << 3));
            float4 u1 = *(const float4*)&xu[(size_t)s1 << 2];
            uint2 r1 = *(const uint2*)(xwb + ((size_t)s1 << 9) + (lane << 3));
            float4 u2 = *(const float4*)&xu[(size_t)s2 << 2];
            uint2 r2 = *(const uint2*)(xwb + ((size_t)s2 << 9) + (lane << 3));
            float4 u3 = *(const float4*)&xu[(size_t)s3 << 2];
            uint2 r3 = *(const uint2*)(xwb + ((size_t)s3 << 9) + (lane << 3));
            acc += term_bf16(xd, u0, r0, c0, c1, c2, c3);
            acc += term_bf16(xd, u1, r1, c0, c1, c2, c3);
            acc += term_bf16(xd, u2, r2, c0, c1, c2, c3);
            acc += term_bf16(xd, u3, r3, c0, c1, c2, c3);
        }
        for (; i < end; i++) {
            int s0 = srcs[i];
            float4 u0 = *(const float4*)&xu[(size_t)s0 << 2];
            uint2 r0 = *(const uint2*)(xwb + ((size_t)s0 << 9) + (lane << 3));
            acc += term_bf16(xd, u0, r0, c0, c1, c2, c3);
        }
    }

    float v = acc / (float)cnt + bias[lane];
    if (RELU_BN) v = fmaxf(v, 0.f);
    y[(size_t)d * 64 + lane] = v;

    if (RELU_BN) {
        sbuf[wid][lane] = v;
        sqbuf[wid][lane] = v * v;
        __syncthreads();
        if (threadIdx.x < 64) {
            float ts = sbuf[0][threadIdx.x] + sbuf[1][threadIdx.x] + sbuf[2][threadIdx.x] + sbuf[3][threadIdx.x];
            float tq = sqbuf[0][threadIdx.x] + sqbuf[1][threadIdx.x] + sqbuf[2][threadIdx.x] + sqbuf[3][threadIdx.x];
            int p = blockIdx.x & 63;
            atomicAdd(&bnpart[p * 128 + threadIdx.x], ts);
            atomicAdd(&bnpart[p * 128 + 64 + threadIdx.x], tq);
        }
    }
}

extern "C" void kernel_launch(void* const* d_in, const int* in_sizes, int n_in,
                              void* d_out, int out_size, void* d_ws, size_t ws_size,
                              hipStream_t stream) {
    const float* x    = (const float*)d_in[0];
    const int*   ei   = (const int*)d_in[1];
    const int*   esrc = ei;
    const int*   edst = ei + NE;
    const float* w0 = (const float*)d_in[2];
    const float* u0 = (const float*)d_in[3];
    const float* c0 = (const float*)d_in[4];
    const float* b0 = (const float*)d_in[5];
    const float* w1 = (const float*)d_in[6];
    const float* u1 = (const float*)d_in[7];
    const float* c1 = (const float*)d_in[8];
    const float* b1 = (const float*)d_in[9];
    const float* w2 = (const float*)d_in[10];
    const float* u2 = (const float*)d_in[11];
    const float* c2 = (const float*)d_in[12];
    const float* b2 = (const float*)d_in[13];
    const float* g0 = (const float*)d_in[14];
    const float* be0= (const float*)d_in[15];
    const float* g1 = (const float*)d_in[16];
    const float* be1= (const float*)d_in[17];
    float* out = (float*)d_out;

    char* ws = (char*)d_ws;
    size_t off = 0;
    auto alloc = [&](size_t bytes) { char* p = ws + off; off += (bytes + 255) & ~(size_t)255; return p; };
    // ints + bnpart0 + bnpart1 adjacent -> single zeroing memset
    int*            ints    = (int*)alloc((size_t)(NN + 1) * sizeof(int));  // deg | gcount
    int*            deg     = ints;
    int*            gcount  = ints + NN;
    float*          bnpart0 = (float*)alloc(64 * 128 * sizeof(float));
    float*          bnpart1 = (float*)alloc(64 * 128 * sizeof(float));
    size_t zero_bytes = (size_t)((char*)bnpart1 - (char*)ints) + 64 * 128 * sizeof(float);
    float*          xu      = (float*)alloc((size_t)NN * 4 * sizeof(float));
    float*          y       = (float*)alloc((size_t)NN * 64 * sizeof(float));
    unsigned char*  xwb     = (unsigned char*)alloc((size_t)NN * 512);  // bf16 stride; fp8 layers use 256B stride
    int*            soff    = (int*)alloc((size_t)NN * sizeof(int));
    int*            cursor  = (int*)alloc((size_t)NN * sizeof(int));
    int*            srcs    = (int*)alloc((size_t)ET * sizeof(int));

    const int EG = (ET + 255) / 256;
    const int XG = (NN + 15) / 16;

    // ---- CSR build (dst-sorted; shared by all 3 layers) ----
    hipMemsetAsync(ints, 0, zero_bytes, stream);
    hist_kernel<<<EG, 256, 0, stream>>>(edst, deg);
    scan_atomic<<<NBLK_SCAN, 256, 0, stream>>>(deg, soff, cursor, gcount);
    scatter_kernel<<<EG, 256, 0, stream>>>(esrc, edst, cursor, srcs);

    // ---- layer 0 (D=32, no input BN, fp8 messages) ----
    xw_kernel<32, false, true><<<XG, 256, 0, stream>>>(x, w0, u0, nullptr, nullptr, nullptr, xwb, xu);
    edge_kernel<true, true><<<NN / 4, 256, 0, stream>>>(soff, deg, srcs, xwb, xu, c0, b0, y, bnpart0);

    // ---- layer 1 (D=64, BN0 folded into xw, fp8 messages) ----
    xw_kernel<64, true, true><<<XG, 256, 0, stream>>>(y, w1, u1, bnpart0, g0, be0, xwb, xu);
    edge_kernel<true, true><<<NN / 4, 256, 0, stream>>>(soff, deg, srcs, xwb, xu, c1, b1, y, bnpart1);

    // ---- layer 2 (D=64, BN1 folded into xw, bf16 messages, raw output) ----
    xw_kernel<64, true, false><<<XG, 256, 0, stream>>>(y, w2, u2, bnpart1, g1, be1, xwb, xu);
    edge_kernel<false, false><<<NN / 4, 256, 0, stream>>>(soff, deg, srcs, xwb, xu, c2, b2, out, nullptr);
}